// Round 13
// baseline (1920.182 us; speedup 1.0000x reference)
//
#include <hip/hip_runtime.h>
#include <stdint.h>

#define Bb   8
#define Nn   8192
#define CIN  64
#define COUT 128
#define Mm   2048
#define KNN  16
#define NTOT (Bb*Nn)   // 65536 rows
#define NCONS 248      // consumer blocks
#define PSTR 8         // idxpub stride (ull) -> one slot per 64B line

typedef unsigned long long ull;
typedef float v2f __attribute__((ext_vector_type(2)));

#define MAGIC 0x55AA1234u

// ---------------- ws layout (bytes) ----------------
// h        : [0,         33554432)   float 65536x128
// idxpub   : [33619968,  34668544)   ull   8x2048x8 (64B-strided slots)
// stats    : [35717120,  35718144)   float sum[128], sumsq[128]
// done     : [35718144,  35718148)   uint  gemm-done counter
// initflag : [35718148,  35718152)   uint  MAGIC once stats/done zeroed
//
// LDS RULE (R2-R4): static LDS <= 98,816 B per WG.
// SYNC RULES: s_barrier beats LDS spin (R8); fps wants 4 waves (R10);
// uniform broadcast beats divergent LDS gather (R11/R12).
// R13 theory: publish store-ack drain at __syncthreads (vmcnt(0)) +
// consumer poll line-contention is the hidden ~1300 cyc/iter -> pad
// slots to 1/line and use lgkmcnt-only barrier in the fps loop.

__device__ __forceinline__ v2f pk_add(v2f a, v2f b)
{ v2f d; asm("v_pk_add_f32 %0, %1, %2" : "=v"(d) : "v"(a), "v"(b)); return d; }
__device__ __forceinline__ v2f pk_mul(v2f a, v2f b)
{ v2f d; asm("v_pk_mul_f32 %0, %1, %2" : "=v"(d) : "v"(a), "v"(b)); return d; }

// Wave64 float-max reduce (R6/R7-proven).
__device__ __forceinline__ float wave_max16(float x)
{
    int v = __float_as_int(x), t;
    t = __builtin_amdgcn_update_dpp(v, v, 0x111, 0xf, 0xf, false); // row_shr:1
    v = __float_as_int(fmaxf(__int_as_float(v), __int_as_float(t)));
    t = __builtin_amdgcn_update_dpp(v, v, 0x112, 0xf, 0xf, false); // row_shr:2
    v = __float_as_int(fmaxf(__int_as_float(v), __int_as_float(t)));
    t = __builtin_amdgcn_update_dpp(v, v, 0x114, 0xf, 0xf, false); // row_shr:4
    v = __float_as_int(fmaxf(__int_as_float(v), __int_as_float(t)));
    t = __builtin_amdgcn_update_dpp(v, v, 0x118, 0xf, 0xf, false); // row_shr:8
    v = __float_as_int(fmaxf(__int_as_float(v), __int_as_float(t)));
    unsigned r0 = (unsigned)__builtin_amdgcn_readlane(v, 15);
    unsigned r1 = (unsigned)__builtin_amdgcn_readlane(v, 31);
    unsigned r2 = (unsigned)__builtin_amdgcn_readlane(v, 47);
    unsigned r3 = (unsigned)__builtin_amdgcn_readlane(v, 63);
    unsigned m0 = r0 > r1 ? r0 : r1;
    unsigned m1 = r2 > r3 ? r2 : r3;
    unsigned mm = m0 > m1 ? m0 : m1;
    return __uint_as_float(mm);
}

// d2 key for topk (R5-proven): sortable u64, tie -> lower index.
__device__ __forceinline__ ull d2key(
    float qx, float qy, float qz, float qn, float x, float y, float z, int j)
{
    float dot = __fadd_rn(__fadd_rn(__fmul_rn(qx, x), __fmul_rn(qy, y)),
                          __fmul_rn(qz, z));
    float cn  = __fadd_rn(__fadd_rn(__fmul_rn(x, x), __fmul_rn(y, y)),
                          __fmul_rn(z, z));
    float d2  = __fadd_rn(__fsub_rn(qn, __fadd_rn(dot, dot)), cn);
    unsigned int bits = __float_as_uint(d2);
    unsigned int u = bits ^ (((unsigned int)((int)bits >> 31)) | 0x80000000u);
    return ((ull)u << 32) | (unsigned int)j;
}

// ============================================================
// SINGLE MEGAKERNEL (256 blocks x 256 thr, 1/CU co-resident):
//  blocks 0..7   : FPS (R12-proven body) with (a) lgkmcnt-only
//                  loop barrier — publish store never drained on
//                  the critical path — and (b) 64B-strided
//                  publish slots.
//  blocks 8..255 : block 8 zeroes stats/done + releases initflag.
//                  Phase A = grid-strided gemm + stats atomics +
//                  done-counter release/acquire. Phase B = fused
//                  kNN + gather + p2out writes.
// Deadlock-free: fps never waits; consumers signal before waiting.
// ============================================================
__global__ __launch_bounds__(256, 1)
void mega_kernel(const float* __restrict__ p1, float* __restrict__ p2out,
                 const float* __restrict__ x, const float* __restrict__ W,
                 const float* __restrict__ gamma, const float* __restrict__ beta,
                 float* __restrict__ h, float* __restrict__ stats,
                 unsigned int* done, unsigned int* initflag,
                 ull* idxpub, float* __restrict__ y)
{
    __shared__ float px[Nn], py[Nn], pz[Nn];        // 96 KB
    __shared__ alignas(16) ull wkey[2][4];          // + 64 B
    const int tid = threadIdx.x;
    const int w = tid >> 6, lane = tid & 63;

    if (blockIdx.x < 8) {
        // ---------------- FPS path ----------------
        const int b = blockIdx.x;
        const float* pb = p1 + b * Nn * 3;

        for (int i = tid; i < Nn * 3; i += 256) {
            float v = pb[i];
            int pt = i / 3;
            int c  = i - pt * 3;
            if (c == 0) px[pt] = v; else if (c == 1) py[pt] = v; else pz[pt] = v;
        }
        __syncthreads();

        v2f ppx[16], ppy[16], ppz[16], mind[16];
#pragma unroll
        for (int i = 0; i < 16; ++i) {
            int j0 = tid * 32 + 2 * i;               // blocked mapping
            ppx[i] = (v2f){px[j0], px[j0 + 1]};
            ppy[i] = (v2f){py[j0], py[j0 + 1]};
            ppz[i] = (v2f){pz[j0], pz[j0 + 1]};
            mind[i] = (v2f){1e10f, 1e10f};
        }

        float lx = px[0], ly = py[0], lz = pz[0];
        if (tid == 0) {
            __hip_atomic_store(&idxpub[(b * Mm) * PSTR], ((ull)MAGIC << 32) | 0ull,
                               __ATOMIC_RELAXED, __HIP_MEMORY_SCOPE_AGENT);
        }

        for (int m = 1; m < Mm; ++m) {
            const int buf = m & 1;
            float nx = -lx, ny = -ly, nz = -lz;     // exact sign flip
            v2f nx2 = (v2f){nx, nx}, ny2 = (v2f){ny, ny}, nz2 = (v2f){nz, nz};
            float bv0 = -1.0f, bv1 = -1.0f; int bj0 = 0, bj1 = 1;
#pragma unroll
            for (int i = 0; i < 16; ++i) {
                v2f dx = pk_add(ppx[i], nx2);       // == ppx - lx, bitwise
                v2f dy = pk_add(ppy[i], ny2);
                v2f dz = pk_add(ppz[i], nz2);
                v2f s  = pk_add(pk_add(pk_mul(dx, dx), pk_mul(dy, dy)),
                                pk_mul(dz, dz));    // ((dx2+dy2)+dz2)
                float m0 = fminf(mind[i].x, s.x);
                float m1 = fminf(mind[i].y, s.y);
                mind[i].x = m0; mind[i].y = m1;
                if (m0 > bv0) { bv0 = m0; bj0 = 2 * i; }
                if (m1 > bv1) { bv1 = m1; bj1 = 2 * i + 1; }
            }
            float bestv; int bestj;
            if (bv1 > bv0 || (bv1 == bv0 && bj1 < bj0)) { bestv = bv1; bestj = bj1; }
            else                                        { bestv = bv0; bestj = bj0; }
            bestj += tid * 32;

            float wv = wave_max16(bestv);
            ull tie = __ballot(bestv == wv);
            int low = __ffsll((long long)tie) - 1;   // lowest lane = lowest index
            if (lane == low) {
                wkey[buf][w] = ((ull)__float_as_uint(wv) << 32) |
                               (unsigned int)(~(unsigned int)bestj);
            }
            // LDS-visibility-only barrier: do NOT drain the publish store
            asm volatile("s_waitcnt lgkmcnt(0)\n\ts_barrier" ::: "memory");

            ull k0 = wkey[buf][0], k1 = wkey[buf][1];
            ull k2 = wkey[buf][2], k3 = wkey[buf][3];
            ull k01 = k0 > k1 ? k0 : k1;
            ull k23 = k2 > k3 ? k2 : k3;
            ull fk  = k01 > k23 ? k01 : k23;
            int jw = (int)(~(unsigned int)fk);
            if (tid == 0) {   // publish early; ack never gates a barrier now
                __hip_atomic_store(&idxpub[(b * Mm + m) * PSTR],
                                   ((ull)MAGIC << 32) | (ull)(unsigned)jw,
                                   __ATOMIC_RELAXED, __HIP_MEMORY_SCOPE_AGENT);
            }
            lx = px[jw]; ly = py[jw]; lz = pz[jw];   // uniform broadcast reads
        }
        return;
    }

    // ============== consumer: init + Phase A = gemm + stats ==============
    const int cb = blockIdx.x - 8;      // 0..247
    const int cp = lane;                // channel pair = 2cp, 2cp+1

    if (blockIdx.x == 8) {              // zero stats/done, release initflag
        if (tid < 256) stats[tid] = 0.0f;
        if (tid == 0) *done = 0u;
        __syncthreads();
        if (tid == 0)
            __hip_atomic_store(initflag, MAGIC, __ATOMIC_RELEASE,
                               __HIP_MEMORY_SCOPE_AGENT);
    }

    {
        const float4* w0 = (const float4*)(W + (cp * 2) * CIN);
        const float4* w1 = (const float4*)(W + (cp * 2 + 1) * CIN);
        float s0 = 0.f, s1 = 0.f, q0 = 0.f, q1 = 0.f;
        for (int r0 = cb * 16 + w * 4; r0 < NTOT; r0 += NCONS * 16) {
            const float4* xp = (const float4*)(x + r0 * CIN);
            float a[4][2];
#pragma unroll
            for (int r = 0; r < 4; ++r) { a[r][0] = 0.f; a[r][1] = 0.f; }
#pragma unroll
            for (int k = 0; k < CIN / 4; ++k) {
                float4 wa = w0[k], wb = w1[k];
#pragma unroll
                for (int r = 0; r < 4; ++r) {
                    float4 xv = xp[r * 16 + k];
                    a[r][0] = fmaf(xv.x, wa.x, fmaf(xv.y, wa.y, fmaf(xv.z, wa.z, fmaf(xv.w, wa.w, a[r][0]))));
                    a[r][1] = fmaf(xv.x, wb.x, fmaf(xv.y, wb.y, fmaf(xv.z, wb.z, fmaf(xv.w, wb.w, a[r][1]))));
                }
            }
#pragma unroll
            for (int r = 0; r < 4; ++r) {
                *(float2*)(h + (r0 + r) * COUT + cp * 2) = make_float2(a[r][0], a[r][1]);
                s0 += a[r][0]; s1 += a[r][1];
                q0 = fmaf(a[r][0], a[r][0], q0); q1 = fmaf(a[r][1], a[r][1], q1);
            }
        }
        float4* comb = (float4*)px;                  // [4][64], restaged later
        comb[w * 64 + cp] = make_float4(s0, s1, q0, q1);
        __syncthreads();
        if (tid == 0) {    // wait for stats zeroed (block 8; long done by now)
            while (__hip_atomic_load(initflag, __ATOMIC_ACQUIRE,
                                     __HIP_MEMORY_SCOPE_AGENT) != MAGIC)
                __builtin_amdgcn_s_sleep(2);
        }
        __syncthreads();
        if (tid < 64) {
            float4 t = comb[cp];
#pragma unroll
            for (int j = 1; j < 4; ++j) {
                float4 o = comb[j * 64 + cp];
                t.x += o.x; t.y += o.y; t.z += o.z; t.w += o.w;
            }
            atomicAdd(&stats[2 * cp], t.x);       atomicAdd(&stats[2 * cp + 1], t.y);
            atomicAdd(&stats[128 + 2 * cp], t.z); atomicAdd(&stats[128 + 2 * cp + 1], t.w);
        }
        __syncthreads();
        if (tid == 0) {
            __hip_atomic_fetch_add(done, 1u, __ATOMIC_RELEASE,
                                   __HIP_MEMORY_SCOPE_AGENT);
            while (__hip_atomic_load(done, __ATOMIC_ACQUIRE,
                                     __HIP_MEMORY_SCOPE_AGENT) < NCONS)
                __builtin_amdgcn_s_sleep(2);
        }
        __syncthreads();   // all h stores + stats adds now visible
    }

    // per-lane BN scale/bias (same formula as proven finalize)
    float sc0, sc1, bi0, bi1;
    {
        float mean0 = stats[2 * cp] * (1.0f / 65536.0f);
        float mean1 = stats[2 * cp + 1] * (1.0f / 65536.0f);
        float var0  = stats[128 + 2 * cp] * (1.0f / 65536.0f) - mean0 * mean0;
        float var1  = stats[128 + 2 * cp + 1] * (1.0f / 65536.0f) - mean1 * mean1;
        sc0 = gamma[2 * cp] / sqrtf(var0 + 1e-5f);
        sc1 = gamma[2 * cp + 1] / sqrtf(var1 + 1e-5f);
        bi0 = beta[2 * cp] - mean0 * sc0;
        bi1 = beta[2 * cp + 1] - mean1 * sc1;
    }

    // ============== consumer: Phase B = fused kNN + gather + p2 ==============
    const int b = cb / 31;              // 31 blocks per batch
    const int k = cb - b * 31;          // query residue mod 31
    const float* pb = p1 + b * Nn * 3;

    for (int i = tid; i < Nn * 3; i += 256) {
        float v = pb[i];
        int pt = i / 3;
        int c  = i - pt * 3;
        if (c == 0) px[pt] = v; else if (c == 1) py[pt] = v; else pz[pt] = v;
    }
    __syncthreads();

    const int c0 = lane * 2;
    const ull INV = ~0ull;

    for (int t = w; k + 31 * t < Mm; t += 4) {
        const int m = k + 31 * t;
        const int qrow = b * Mm + m;

        ull pv;
        for (;;) {
            pv = __hip_atomic_load(&idxpub[qrow * PSTR], __ATOMIC_RELAXED,
                                   __HIP_MEMORY_SCOPE_AGENT);
            if ((unsigned)(pv >> 32) == MAGIC) break;
            __builtin_amdgcn_s_sleep(2);
        }
        const int jq = (int)(pv & 0x1FFFull);
        const float qx = px[jq], qy = py[jq], qz = pz[jq];
        if (lane == 0) {   // p2 output (bitwise == p1 coords)
            p2out[qrow * 3]     = qx;
            p2out[qrow * 3 + 1] = qy;
            p2out[qrow * 3 + 2] = qz;
        }
        const float qn = __fadd_rn(__fadd_rn(__fmul_rn(qx, qx), __fmul_rn(qy, qy)),
                                   __fmul_rn(qz, qz));

        ull k1 = INV, k2 = INV, k3 = INV;
#pragma unroll 4
        for (int i = 0; i < 128; ++i) {
            int j = lane + (i << 6);
            ull key = d2key(qx, qy, qz, qn, px[j], py[j], pz[j], j);
            bool b1 = key < k1, b2 = key < k2, b3 = key < k3;
            ull n1 = b1 ? key : k1;
            ull n2 = b1 ? k1 : (b2 ? key : k2);
            ull n3 = b2 ? k2 : (b3 ? key : k3);
            k1 = n1; k2 = n2; k3 = n3;
        }

        float a0 = -1e30f, a1 = -1e30f;
        for (int r = 0; r < KNN; ++r) {
            ull wk = k1;
#pragma unroll
            for (int off = 1; off < 64; off <<= 1) {
                ull ok = __shfl_xor(wk, off, 64);
                wk = ok < wk ? ok : wk;
            }
            const int n = (int)(unsigned int)(wk & 0xFFFFFFFFull);
            const float2 v = *(const float2*)(h + (((b << 13) + n) * COUT) + c0);
            if (k1 == wk) { k1 = k2; k2 = k3; k3 = INV; }
            if (k1 == INV) {   // rare: rebuild top-3 among keys > wk
                for (int i = 0; i < 128; ++i) {
                    int j = lane + (i << 6);
                    ull key = d2key(qx, qy, qz, qn, px[j], py[j], pz[j], j);
                    if (key > wk) {
                        bool b1 = key < k1, b2 = key < k2, b3 = key < k3;
                        ull n1 = b1 ? key : k1;
                        ull n2 = b1 ? k1 : (b2 ? key : k2);
                        ull n3 = b2 ? k2 : (b3 ? key : k3);
                        k1 = n1; k2 = n2; k3 = n3;
                    }
                }
            }
            a0 = fmaxf(a0, fmaf(v.x, sc0, bi0));
            a1 = fmaxf(a1, fmaf(v.y, sc1, bi1));
        }
        a0 = fmaxf(a0, 0.0f); a1 = fmaxf(a1, 0.0f);
        *(float2*)(y + qrow * COUT + c0) = make_float2(a0, a1);
    }
}

extern "C" void kernel_launch(void* const* d_in, const int* in_sizes, int n_in,
                              void* d_out, int out_size, void* d_ws, size_t ws_size,
                              hipStream_t stream)
{
    const float* x     = (const float*)d_in[0];
    const float* p1    = (const float*)d_in[1];
    const float* W     = (const float*)d_in[2];
    const float* gamma = (const float*)d_in[3];
    const float* beta  = (const float*)d_in[4];

    float* y  = (float*)d_out;                       // (8,2048,128)
    float* p2 = (float*)d_out + Bb * Mm * COUT;      // (8,2048,3)

    char*  ws     = (char*)d_ws;
    float* h      = (float*)ws;
    ull*   idxpub = (ull*)(ws + 33619968);
    float* stats  = (float*)(ws + 35717120);
    unsigned int* done     = (unsigned int*)(ws + 35718144);
    unsigned int* initflag = (unsigned int*)(ws + 35718148);

    mega_kernel<<<256, 256, 0, stream>>>(p1, p2, x, W, gamma, beta,
                                         h, stats, done, initflag, idxpub, y);
}